// Round 1
// baseline (82.929 us; speedup 1.0000x reference)
//
#include <hip/hip_runtime.h>
#include <math.h>

// Problem constants (from reference setup_inputs)
#define BATCH 64
#define NPATCH 784
#define DIM 768
#define KSEL 392          // int(784 * 0.5)
#define SIDE 28
#define HWDIM 448
#define NPIX (HWDIM*HWDIM)     // 200704
#define PARTS 49               // blocks per batch for COG partial reduction
#define PIX_PER_PART (NPIX/PARTS)  // 4096
#define GSPLIT 4               // selection blocks per batch
#define IPB 196                // elements per selection block (784/4)

// ---------------------------------------------------------------------------
// Kernel 1: partial COG sums per (batch, part). Deterministic fixed-order
// double accumulation; per-element float32 products emulate numpy's
// (line_drawing * y) rounding before the sum.
// ---------------------------------------------------------------------------
__global__ void cog_partial(const float* __restrict__ ld, double* __restrict__ part) {
    const int blk = blockIdx.x;
    const int b = blk / PARTS;
    const int p = blk % PARTS;
    const int t = threadIdx.x;

    const float* base = ld + (size_t)b * NPIX + (size_t)p * PIX_PER_PART;
    double s = 0.0, sy = 0.0, sx = 0.0;

    // 4096 pixels per part = 1024 float4; 256 threads x 4 float4 each.
    // 448 % 4 == 0 so each float4 stays within one image row.
    #pragma unroll
    for (int r = 0; r < 4; ++r) {
        const int f4 = r * 256 + t;                 // 0..1023
        const int pix = p * PIX_PER_PART + f4 * 4;  // within-batch pixel idx
        const float4 v = reinterpret_cast<const float4*>(base)[f4];
        const int i = pix / HWDIM;
        const int j = pix - i * HWDIM;
        // linspace(0,1,448)[i] as numpy computes it: f32(i/447)
        const float yf = (float)((double)i / 447.0);
        const float x0 = (float)((double)(j + 0) / 447.0);
        const float x1 = (float)((double)(j + 1) / 447.0);
        const float x2 = (float)((double)(j + 2) / 447.0);
        const float x3 = (float)((double)(j + 3) / 447.0);
        s  += (double)v.x + (double)v.y + (double)v.z + (double)v.w;
        sy += (double)__fmul_rn(v.x, yf) + (double)__fmul_rn(v.y, yf)
            + (double)__fmul_rn(v.z, yf) + (double)__fmul_rn(v.w, yf);
        sx += (double)__fmul_rn(v.x, x0) + (double)__fmul_rn(v.y, x1)
            + (double)__fmul_rn(v.z, x2) + (double)__fmul_rn(v.w, x3);
    }

    __shared__ double red[3 * 256];
    red[t] = s; red[256 + t] = sy; red[512 + t] = sx;
    __syncthreads();
    for (int off = 128; off > 0; off >>= 1) {
        if (t < off) {
            red[t]       += red[t + off];
            red[256 + t] += red[256 + t + off];
            red[512 + t] += red[512 + t + off];
        }
        __syncthreads();
    }
    if (t == 0) {
        double* dst = part + (size_t)(b * PARTS + p) * 3;
        dst[0] = red[0]; dst[1] = red[256]; dst[2] = red[512];
    }
}

// ---------------------------------------------------------------------------
// Kernel 2: combine partials -> cog[b] = (cy, cx). Fixed order, deterministic.
// ---------------------------------------------------------------------------
__global__ void cog_final(const double* __restrict__ part, float* __restrict__ cog) {
    const int b = threadIdx.x;
    if (b < BATCH) {
        double s = 0.0, sy = 0.0, sx = 0.0;
        for (int p = 0; p < PARTS; ++p) {
            const double* src = part + (size_t)(b * PARTS + p) * 3;
            s += src[0]; sy += src[1]; sx += src[2];
        }
        // reference: total = sum + 1e-6 (f32); cog = num / total (f32)
        const float total = __fadd_rn((float)s, 1e-6f);
        cog[b * 2 + 0] = __fdiv_rn((float)sy, total);
        cog[b * 2 + 1] = __fdiv_rn((float)sx, total);
    }
}

// ---------------------------------------------------------------------------
// Kernel 3: selection. One block handles 196 of a batch's 784 elements but
// computes the full weighted[784] in LDS. Stable O(N) rank per element exactly
// reproduces lax.top_k tie-breaking (lower index first) and the combined
// (ascending-above, then masked-top-k) path.
// ---------------------------------------------------------------------------
__global__ void select_k(const float* __restrict__ scores, const float* __restrict__ cog,
                         int* __restrict__ sel) {
    const int blk = blockIdx.x;
    const int b = blk / GSPLIT;
    const int g = blk % GSPLIT;
    const int t = threadIdx.x;

    __shared__ float sw[NPATCH];
    __shared__ int redc[256];

    const float cy = cog[b * 2 + 0];
    const float cx = cog[b * 2 + 1];

    int local_above = 0;
    for (int n = t; n < NPATCH; n += 256) {
        const int r = n / SIDE;
        const int c = n - r * SIDE;
        // linspace(0,1,28)[i] = f32(i/27)
        const float gy = (float)((double)r / 27.0);
        const float gx = (float)((double)c / 27.0);
        const float dy = gy - cy;
        const float dx = gx - cx;
        // emulate numpy: dy2, dx2 rounded separately, then summed (no FMA)
        const float dy2 = __fmul_rn(dy, dy);
        const float dx2 = __fmul_rn(dx, dx);
        const float d2 = __fadd_rn(dy2, dx2);
        // -d2 / 0.125 == -8*d2 exactly (power of two); exp in f64 then round
        const float w = (float)exp((double)(-8.0f * d2));
        const float wt = __fmul_rn(scores[(size_t)b * NPATCH + n], w);
        sw[n] = wt;
        local_above += (wt > 0.3f) ? 1 : 0;
    }

    redc[t] = local_above;
    __syncthreads();
    for (int off = 128; off > 0; off >>= 1) {
        if (t < off) redc[t] += redc[t + off];
        __syncthreads();
    }
    const int count = redc[0];
    const bool use_topk = (count == 0) || (count >= KSEL);

    const int i = g * IPB + t;
    if (t < IPB && i < NPATCH) {
        const float wi = sw[i];
        const bool above_i = wi > 0.3f;
        int r_all = 0, r_below = 0, r_pre = 0;
        for (int j = 0; j < NPATCH; ++j) {
            const float wj = sw[j];                       // LDS broadcast
            const bool gt = (wj > wi) || ((wj == wi) && (j < i));
            const bool aj = wj > 0.3f;
            r_all   += gt ? 1 : 0;
            r_below += (gt && !aj) ? 1 : 0;
            r_pre   += (aj && (j < i)) ? 1 : 0;
        }
        int* selb = sel + (size_t)b * KSEL;
        if (use_topk) {
            if (r_all < KSEL) selb[r_all] = i;            // stable descending top-k
        } else if (above_i) {
            selb[r_pre] = i;                              // ascending above indices
        } else {
            const int pos = count + r_below;              // masked top-k remainder
            if (pos < KSEL) selb[pos] = i;
        }
    }
}

// ---------------------------------------------------------------------------
// Kernel 4: gather + add. One block per output row; 192 threads x float4 = 768.
// ---------------------------------------------------------------------------
__global__ void gather_add(const float* __restrict__ magno, const float* __restrict__ pos,
                           const int* __restrict__ sel, float* __restrict__ out) {
    const int row = blockIdx.x;          // 0 .. BATCH*KSEL-1
    const int t = threadIdx.x;           // 0 .. 191
    const int b = row / KSEL;
    const int s = sel[row];

    const float4* src = reinterpret_cast<const float4*>(magno + ((size_t)b * NPATCH + s) * DIM);
    const float4* pp  = reinterpret_cast<const float4*>(pos + (size_t)(s + 1) * DIM);
    const float4 a = src[t];
    const float4 p = pp[t];
    float4 o;
    o.x = a.x + p.x; o.y = a.y + p.y; o.z = a.z + p.z; o.w = a.w + p.w;
    reinterpret_cast<float4*>(out + (size_t)row * DIM)[t] = o;
}

extern "C" void kernel_launch(void* const* d_in, const int* in_sizes, int n_in,
                              void* d_out, int out_size, void* d_ws, size_t ws_size,
                              hipStream_t stream) {
    const float* magno  = (const float*)d_in[0];  // [64, 784, 768]
    const float* vit    = (const float*)d_in[1];  // [1, 785, 768]
    const float* scores = (const float*)d_in[2];  // [64, 784]
    const float* ld     = (const float*)d_in[3];  // [64, 1, 448, 448]
    float* out = (float*)d_out;                   // [64, 392, 768]

    // workspace layout
    double* partials = (double*)d_ws;                                   // 64*49*3 doubles
    float*  cog = (float*)((char*)d_ws + (size_t)BATCH * PARTS * 3 * sizeof(double));
    int*    sel = (int*)((char*)cog + (size_t)BATCH * 2 * sizeof(float));

    cog_partial<<<dim3(BATCH * PARTS), dim3(256), 0, stream>>>(ld, partials);
    cog_final<<<dim3(1), dim3(64), 0, stream>>>(partials, cog);
    select_k<<<dim3(BATCH * GSPLIT), dim3(256), 0, stream>>>(scores, cog, sel);
    gather_add<<<dim3(BATCH * KSEL), dim3(192), 0, stream>>>(magno, vit, sel, out);
}